// Round 4
// baseline (11136.047 us; speedup 1.0000x reference)
//
#include <hip/hip_runtime.h>
#include <hip/hip_bf16.h>
#include <math.h>

static constexpr int BB = 4;
static constexpr int NN = 20000;
static constexpr int CC = 256;
static constexpr int SS = 1024;   // NUM_SAMPLE
static constexpr int NV = 300;    // NUM_VIEW

// output offsets (floats) in d_out, concatenated in reference return order
static constexpr size_t O0 = 0;                     // objectness (B,2,N)
static constexpr size_t O1 = O0 + (size_t)BB*2*NN;  // graspness (B,N)
static constexpr size_t O2 = O1 + (size_t)BB*NN;    // graspable_xyz (B,S,3)
static constexpr size_t O3 = O2 + (size_t)BB*SS*3;  // graspable_inds (B,S) as float
static constexpr size_t O4 = O3 + (size_t)BB*SS;    // graspable_features (B,C,S)
static constexpr size_t O5 = O4 + (size_t)BB*CC*SS; // fp2_graspness (B,S)
static constexpr size_t O6 = O5 + (size_t)BB*SS;    // vp_xyz (B,S,3)
static constexpr size_t O7 = O6 + (size_t)BB*SS*3;  // top_view_inds (B,S) as float
static constexpr size_t O8 = O7 + (size_t)BB*SS;    // vp_rot (B,S,3,3)

typedef float v2f __attribute__((ext_vector_type(2)));

// constants shared with mega's gemm2 epilogue layout
static constexpr int KC = 32;     // legacy offset constant (tv placement)
static constexpr int SW_LD = 260; // legacy offset constant
static constexpr int PS_LD = 68;  // padded LDS row for psum

// ---------------------------------------------------------------------------
// GEMM1 v4 "SGPR-broadcast": zero LDS in the main loop.
//  - wave w owns m-rows [64w, 64w+64); lane l owns column n0+l.
//  - W operand is wave-uniform: hipcc scalarizes the uniform float4 loads of
//    W1[m][k0..k0+15] (row-major contiguous) to s_load (SMEM pipe, K$/L2).
//  - X: one column/lane, 16 VGPRs per k-chunk, coalesced global loads
//    (4-wave redundancy absorbed by L1).
//  - per-(m,n) k-chain: ascending fmaf, identical to prior kernels.
//  - epilogue reproduces the EXACT prior psum topology (32 groups of 8 m,
//    same chain order, ascending 32-partial reduction) => o0/o1 BIT-IDENTICAL.
// ---------------------------------------------------------------------------
static constexpr int G1_TN = 64;

__global__ __launch_bounds__(256, 2) void gemm_fused(
    const float* __restrict__ X,
    const float* __restrict__ W1, const float* __restrict__ B1v,
    const float* __restrict__ Gv, const float* __restrict__ BEv,
    const float* __restrict__ Mv, const float* __restrict__ Vv,
    const float* __restrict__ W2, const float* __restrict__ B2v,
    float* __restrict__ o0, float* __restrict__ o1)
{
    __shared__ alignas(16) float psum[3*32*PS_LD];   // 26112 B
    __shared__ float gout[192];

    const int t  = threadIdx.x;
    const int b  = blockIdx.y;
    const int n0 = blockIdx.x * G1_TN;
    const int w  = t >> 6;                 // wave 0..3 -> m-rows [64w, 64w+64)
    const int l  = t & 63;                 // lane -> column n0+l
    const int col = n0 + l;
    const bool valid = col < NN;
    const int m0 = w << 6;
    const float* __restrict__ Xb = X + (size_t)b * CC * NN + col;

    float acc[64];
#pragma unroll
    for (int i = 0; i < 64; ++i) acc[i] = 0.f;

    float xc[16];
#pragma unroll
    for (int kk = 0; kk < 16; ++kk)
        xc[kk] = valid ? Xb[(size_t)kk * NN] : 0.f;

    for (int c = 0; c < CC/16; ++c) {
        const int k0 = c << 4;
        float xn[16];
        if (c < CC/16 - 1) {
#pragma unroll
            for (int kk = 0; kk < 16; ++kk)
                xn[kk] = valid ? Xb[(size_t)(k0 + 16 + kk) * NN] : 0.f;
        }
        const float* __restrict__ wbase = W1 + (size_t)m0 * CC + k0;   // wave-uniform
#pragma unroll
        for (int mi = 0; mi < 64; ++mi) {
            const float4 wa = *(const float4*)(wbase + (size_t)mi*CC);
            const float4 wb = *(const float4*)(wbase + (size_t)mi*CC + 4);
            const float4 wc = *(const float4*)(wbase + (size_t)mi*CC + 8);
            const float4 wd = *(const float4*)(wbase + (size_t)mi*CC + 12);
            float a = acc[mi];
            a = fmaf(wa.x, xc[0],  a); a = fmaf(wa.y, xc[1],  a);
            a = fmaf(wa.z, xc[2],  a); a = fmaf(wa.w, xc[3],  a);
            a = fmaf(wb.x, xc[4],  a); a = fmaf(wb.y, xc[5],  a);
            a = fmaf(wb.z, xc[6],  a); a = fmaf(wb.w, xc[7],  a);
            a = fmaf(wc.x, xc[8],  a); a = fmaf(wc.y, xc[9],  a);
            a = fmaf(wc.z, xc[10], a); a = fmaf(wc.w, xc[11], a);
            a = fmaf(wd.x, xc[12], a); a = fmaf(wd.y, xc[13], a);
            a = fmaf(wd.z, xc[14], a); a = fmaf(wd.w, xc[15], a);
            acc[mi] = a;
        }
        if (c < CC/16 - 1) {
#pragma unroll
            for (int kk = 0; kk < 16; ++kk) xc[kk] = xn[kk];
        }
    }

    // epilogue: bn+relu+W2, grouped exactly like the prior psum topology
#pragma unroll
    for (int i2 = 0; i2 < 8; ++i2) {
        float p0 = 0.f, p1 = 0.f, p2 = 0.f;
#pragma unroll
        for (int i = 0; i < 8; ++i) {
            const int mi = i2*8 + i;
            const int m  = m0 + mi;        // == 8*(8w+i2) + i : same groups as before
            float scale = __fdiv_rn(Gv[m], __fsqrt_rn(__fadd_rn(Vv[m], 1e-5f)));
            float shift = __fsub_rn(BEv[m], __fmul_rn(Mv[m], scale));
            float x = __fadd_rn(acc[mi], B1v[m]);
            float y = __fadd_rn(__fmul_rn(x, scale), shift);
            float h = y > 0.f ? y : 0.f;
            p0 = fmaf(W2[m],      h, p0);
            p1 = fmaf(W2[CC+m],   h, p1);
            p2 = fmaf(W2[2*CC+m], h, p2);
        }
        const int g = (w << 3) + i2;
        psum[(0*32 + g)*PS_LD + l] = p0;
        psum[(1*32 + g)*PS_LD + l] = p1;
        psum[(2*32 + g)*PS_LD + l] = p2;
    }
    __syncthreads();
    if (t < 192) {
        int r = t >> 6, cc2 = t & 63;
        float s = 0.f;
#pragma unroll
        for (int ww = 0; ww < 32; ++ww) s = __fadd_rn(s, psum[(r*32 + ww)*PS_LD + cc2]);
        gout[r*64 + cc2] = __fadd_rn(s, B2v[r]);
    }
    __syncthreads();
    if (t < 64) {
        int n = n0 + t;
        if (n < NN) {
            o0[(size_t)b*2*NN + n]      = gout[t];
            o0[(size_t)b*2*NN + NN + n] = gout[64 + t];
            o1[(size_t)b*NN + n]        = gout[128 + t];
        }
    }
}

// ---------------------------------------------------------------------------
// FPS helpers (R6-proven): u64-key DPP wave max, packed-pair scan
// ---------------------------------------------------------------------------
static constexpr int FPS_T = 256;
static constexpr int KAMAX = 20;
static constexpr int CAPA  = FPS_T * KAMAX; // 5120

template<int CTRL>
__device__ __forceinline__ unsigned long long dpp_umax(unsigned long long k) {
    int lo = __builtin_amdgcn_update_dpp(0, (int)(unsigned)k,         CTRL, 0xf, 0xf, false);
    int hi = __builtin_amdgcn_update_dpp(0, (int)(unsigned)(k >> 32), CTRL, 0xf, 0xf, false);
    unsigned long long ok = ((unsigned long long)(unsigned)hi << 32) | (unsigned)lo;
    return ok > k ? ok : k;
}

__device__ __forceinline__ unsigned long long wave_umax_dpp(unsigned long long k) {
    k = dpp_umax<0x111>(k);
    k = dpp_umax<0x112>(k);
    k = dpp_umax<0x114>(k);
    k = dpp_umax<0x118>(k);
    k = dpp_umax<0x142>(k);
    k = dpp_umax<0x143>(k);  // lane 63 has wave max
    return k;
}

__device__ __forceinline__ unsigned long long pack_key(float v, int i) {
    unsigned long long k = (((unsigned long long)__float_as_uint(v)) << 32)
                         | (unsigned long long)(0xFFFFFFFFu - (unsigned)i);
    return (v == -INFINITY) ? 0ull : k;
}

template<int KP>   // pairs of slots per thread
__device__ __forceinline__ void fps_scan_loop(
    int cnt, const float* __restrict__ sxyz,
    unsigned long long (*swk)[4], int* __restrict__ whist)
{
#pragma clang fp contract(off)
    const int t = threadIdx.x;
    const int wave = t >> 6, lane = t & 63;

    v2f X2[KP], Y2[KP], Z2[KP], D2[KP];
#pragma unroll
    for (int jp = 0; jp < KP; ++jp) {
        int g0 = t + ((2*jp) << 8);
        int g1 = g0 + 256;
        bool v0 = g0 < cnt, v1 = g1 < cnt;
        float4 wa = v0 ? *(const float4*)&sxyz[g0*4] : make_float4(0.f,0.f,0.f,0.f);
        float4 wb = v1 ? *(const float4*)&sxyz[g1*4] : make_float4(0.f,0.f,0.f,0.f);
        X2[jp][0] = wa.x; X2[jp][1] = wb.x;
        Y2[jp][0] = wa.y; Y2[jp][1] = wb.y;
        Z2[jp][0] = wa.z; Z2[jp][1] = wb.z;
        D2[jp][0] = v0 ? 1e10f : -INFINITY;
        D2[jp][1] = v1 ? 1e10f : -INFINITY;
    }

    float px = sxyz[0], py = sxyz[1], pz = sxyz[2];

    for (int it = 1; it < SS; ++it) {
        float bv = -INFINITY; int bi = 0x7fffffff;
#pragma unroll
        for (int jp = 0; jp < KP; ++jp) {
            v2f dx = X2[jp] - px;
            v2f dy = Y2[jp] - py;
            v2f dz = Z2[jp] - pz;
            v2f xx = dx*dx, yy = dy*dy;
            v2f sxy = xx + yy;
            v2f zz = dz*dz;
            v2f dd = sxy + zz;              // ((dx^2+dy^2)+dz^2), np order
            float dn0 = fminf(D2[jp][0], dd[0]);
            float dn1 = fminf(D2[jp][1], dd[1]);
            D2[jp][0] = dn0;
            D2[jp][1] = dn1;
            if (dn0 > bv) { bv = dn0; bi = t + ((2*jp)   << 8); }
            if (dn1 > bv) { bv = dn1; bi = t + ((2*jp+1) << 8); }
        }
        unsigned long long key = wave_umax_dpp(pack_key(bv, bi));
        int par = it & 1;
        if (lane == 63) swk[par][wave] = key;
        __syncthreads();
        const ulonglong2* kp = (const ulonglong2*)&swk[par][0];
        ulonglong2 kA = kp[0], kB = kp[1];
        unsigned long long m0 = kA.x > kA.y ? kA.x : kA.y;
        unsigned long long m1 = kB.x > kB.y ? kB.x : kB.y;
        unsigned long long best = m0 > m1 ? m0 : m1;
        int wi = (int)(0xFFFFFFFFu - (unsigned)(best & 0xFFFFFFFFull));
        float4 w4 = *(const float4*)&sxyz[wi*4];
        px = w4.x; py = w4.y; pz = w4.z;
        if (t == 0) whist[it] = wi;
    }
}

// ---------------------------------------------------------------------------
// MEGA kernel (R2-proven): 256 blocks x 256 threads, all co-resident.
//  blocks [0,BB):   compact (mask from o0/o1) -> FPS -> publish inds (release)
//  blocks [BB,256): low-duty spin on done flag, then acquire and either
//                     wid<64:  gemm2 (pipelined dbuf + pk-FMA; W chunk0
//                              loads issued pre-spin) + view/rot epilogue
//                     else:    o2/o4/o5 gathers (single pass: best line reuse)
// ---------------------------------------------------------------------------
__global__ __launch_bounds__(256, 1) void mega_kernel(
    const float* __restrict__ xyz, const float* __restrict__ feats,
    const float* __restrict__ o0, const float* __restrict__ o1,
    const float* __restrict__ c1w, const float* __restrict__ c1b,
    const float* __restrict__ bng, const float* __restrict__ bnb,
    const float* __restrict__ bnm, const float* __restrict__ bnv,
    const float* __restrict__ c2w, const float* __restrict__ c2b,
    int* __restrict__ corig, float* __restrict__ cxg,
    float* __restrict__ cyg, float* __restrict__ czg,
    float* __restrict__ o2, float* __restrict__ o3, float* __restrict__ o4,
    float* __restrict__ o5, float* __restrict__ o6, float* __restrict__ o7,
    float* __restrict__ o8, int* __restrict__ indsp, int* __restrict__ donep)
{
    __shared__ alignas(16) char sm[86272];
    const int t = threadIdx.x;
    const int wave = t >> 6, lane = t & 63;

    if (blockIdx.x < BB) {
        // =================== FPS PRODUCER BLOCK ===================
        const int b = blockIdx.x;
        const size_t bofs = (size_t)b*NN;
        float* sxyz = (float*)sm;                                     // [CAPA*4]
        int*   whist = (int*)(sm + 81920);                            // [SS]
        unsigned long long (*swk)[4] = (unsigned long long (*)[4])(sm + 86016);
        int*   wsum  = (int*)(sm + 86080);                            // [4]
        int*   smisc = (int*)(sm + 86096);                            // running

        // ---- compact: mask recomputed bit-exactly from o0/o1 ----
        if (t == 0) smisc[0] = 0;
        __syncthreads();
        const float* ob0 = o0 + (size_t)b*2*NN;
        const float* ob1 = o1 + (size_t)b*NN;
        for (int base = 0; base < NN; base += 256) {
            int i = base + t;
            bool valid = i < NN;
            float g1 = valid ? ob1[i]      : 0.f;
            float v0 = valid ? ob0[i]      : 0.f;
            float v1 = valid ? ob0[NN + i] : 0.f;
            bool m = valid && (g1 > 0.1f) && (v1 > v0);
            unsigned long long bal = __ballot(m);
            int pre = __popcll(bal & ((1ull << lane) - 1ull));
            if (lane == 0) wsum[wave] = __popcll(bal);
            __syncthreads();
            int offs = smisc[0];
            int tilesum = wsum[0] + wsum[1] + wsum[2] + wsum[3];
            for (int ww = 0; ww < wave; ++ww) offs += wsum[ww];
            if (m) {
                int pos = offs + pre;
                float x = xyz[(bofs + i)*3 + 0];
                float y = xyz[(bofs + i)*3 + 1];
                float z = xyz[(bofs + i)*3 + 2];
                corig[bofs + pos] = i;
                cxg[bofs + pos] = x; cyg[bofs + pos] = y; czg[bofs + pos] = z;
                if (pos < CAPA) {
                    float4 w4 = {x, y, z, 0.f};
                    *(float4*)&sxyz[pos*4] = w4;
                }
            }
            __syncthreads();
            if (t == 0) smisc[0] += tilesum;   // no post-scatter wsum read (race-free)
        }
        __syncthreads();
        const int cnt = smisc[0];

        float* o3b = o3 + (size_t)b*SS;
        int*   oib = indsp + (size_t)b*SS;

        if (cnt <= 0) {
            for (int s = t; s < SS; s += FPS_T) { o3b[s] = 0.f; oib[s] = 0; }
            __syncthreads();
            if (t == 0) {
                __threadfence();
                __hip_atomic_fetch_add(donep, 1, __ATOMIC_RELEASE, __HIP_MEMORY_SCOPE_AGENT);
            }
            return;
        }

        if (t == 0) whist[0] = 0;
        __syncthreads();

        if (cnt <= CAPA) {
            int kat2 = ((cnt + 255) >> 8);
            kat2 = (kat2 + 1) & ~1;
            int kpn = kat2 >> 1;
            switch (kpn) {
                case 1:  fps_scan_loop<1 >(cnt, sxyz, swk, whist); break;
                case 2:  fps_scan_loop<2 >(cnt, sxyz, swk, whist); break;
                case 3:  fps_scan_loop<3 >(cnt, sxyz, swk, whist); break;
                case 4:  fps_scan_loop<4 >(cnt, sxyz, swk, whist); break;
                case 5:  fps_scan_loop<5 >(cnt, sxyz, swk, whist); break;
                case 6:  fps_scan_loop<6 >(cnt, sxyz, swk, whist); break;
                case 7:  fps_scan_loop<7 >(cnt, sxyz, swk, whist); break;
                case 8:  fps_scan_loop<8 >(cnt, sxyz, swk, whist); break;
                case 9:  fps_scan_loop<9 >(cnt, sxyz, swk, whist); break;
                default: fps_scan_loop<10>(cnt, sxyz, swk, whist); break;
            }
        } else {
            // fallback: LDS distances, streamed xyz from global compacted arrays
            float* Dl = sxyz;
            for (int g = t; g < cnt; g += FPS_T) Dl[g] = 1e10f;
            __syncthreads();
            float px = cxg[bofs], py = cyg[bofs], pz = czg[bofs];
            for (int it = 1; it < SS; ++it) {
                float bv = -INFINITY; int bi = 0x7fffffff;
                for (int g = t; g < cnt; g += FPS_T) {
                    float dx = __fsub_rn(cxg[bofs + g], px);
                    float dy = __fsub_rn(cyg[bofs + g], py);
                    float dz = __fsub_rn(czg[bofs + g], pz);
                    float d  = __fadd_rn(__fadd_rn(__fmul_rn(dx,dx), __fmul_rn(dy,dy)), __fmul_rn(dz,dz));
                    float dn = fminf(Dl[g], d);
                    Dl[g] = dn;
                    if (dn > bv) { bv = dn; bi = g; }
                }
                unsigned long long key = wave_umax_dpp(pack_key(bv, bi));
                int par = it & 1;
                if (lane == 63) swk[par][wave] = key;
                __syncthreads();
                const ulonglong2* kp = (const ulonglong2*)&swk[par][0];
                ulonglong2 kA = kp[0], kB = kp[1];
                unsigned long long m0 = kA.x > kA.y ? kA.x : kA.y;
                unsigned long long m1 = kB.x > kB.y ? kB.x : kB.y;
                unsigned long long best = m0 > m1 ? m0 : m1;
                int wi = (int)(0xFFFFFFFFu - (unsigned)(best & 0xFFFFFFFFull));
                px = cxg[bofs + wi]; py = cyg[bofs + wi]; pz = czg[bofs + wi];
                if (t == 0) whist[it] = wi;
            }
        }

        __syncthreads();
        for (int s = t; s < SS; s += FPS_T) {
            int wi  = whist[s];
            int org = corig[bofs + wi];
            oib[s] = org;
            o3b[s] = (float)org;
        }
        __syncthreads();                 // all inds writes issued & drained
        if (t == 0) {
            __threadfence();             // agent-scope flush of this block's stores
            __hip_atomic_fetch_add(donep, 1, __ATOMIC_RELEASE, __HIP_MEMORY_SCOPE_AGENT);
        }
        return;
    }

    // =================== CONSUMER BLOCKS ===================
    const int wid = blockIdx.x - BB;

    // pre-stage gemm2 W chunk-0 loads (independent of producers; in flight
    // during the spin window)
    float4 g2w[4];
    if (wid < 64) {
#pragma unroll
        for (int r = 0; r < 4; ++r) {
            int f  = r*1024 + t*4;
            int m  = f >> 4;
            int kk = f & 15;
            g2w[r] = *(const float4*)&c1w[(size_t)m*CC + kk];
        }
    }

    {
        int* smisc = (int*)(sm + 86096);
        if (t == 0) smisc[1] = 0;
        __syncthreads();
        // low-duty spin (R4/R6-proven clock-friendly point)
        float a = 1.0f + (float)t * 1e-6f, bmul = 1.0000001f, c = 0.f;
        for (int iter = 0; iter < (1 << 22); ++iter) {
#pragma unroll
            for (int u = 0; u < 16; ++u) c = fmaf(a, bmul, c);
            __builtin_amdgcn_s_sleep(8);
            if (t == 0 && (iter & 7) == 0) {
                if (__hip_atomic_load(donep, __ATOMIC_RELAXED, __HIP_MEMORY_SCOPE_AGENT) >= BB)
                    *(volatile int*)&smisc[1] = 1;
            }
            if (*(volatile int*)&smisc[1]) break;
        }
        ((volatile float*)(sm + 86144))[t & 31] = c;   // keep spin live; scratch above live regions
        __syncthreads();
        (void)__hip_atomic_load(donep, __ATOMIC_ACQUIRE, __HIP_MEMORY_SCOPE_AGENT);
    }

    if (wid < 64) {
        // ---------------- gemm2 + view/rot for one 64-col tile ----------------
        const int bi = wid >> 4;
        const int n0 = (wid & 15) << 6;
        constexpr int G2_KC  = 16;
        constexpr int G2_LD  = 260;
        constexpr int G2_TN  = 64;
        constexpr int G2_BUF = G2_KC*G2_LD + G2_KC*G2_TN;  // 5184 floats/buffer

        float* smf  = (float*)sm;                          // 2 buffers: 41472 B
        float* psum = smf;                                 // [3][32][PS_LD] (post-loop alias)
        float* gout = (float*)(sm + 3*32*PS_LD*4);         // [3][64]
        float* tv   = (float*)(sm + KC*SW_LD*4);           // [3][300] (post-loop alias)

        const int tm  = t & 31;
        const int tn  = t >> 5;
        const int kk0 = t >> 4;          // F-stage row (0..15)
        const int j0  = (t*4) & 63;      // F-stage col base (4-aligned)

        const int4 sidx4 = *(const int4*)&indsp[(bi << 10) + n0 + j0];
        const size_t frow_base = (size_t)bi * CC;

        v2f acc2[8][4];
#pragma unroll
        for (int i = 0; i < 8; ++i)
#pragma unroll
            for (int jp = 0; jp < 4; ++jp) acc2[i][jp] = (v2f){0.f, 0.f};

        float4 wreg[4] = {g2w[0], g2w[1], g2w[2], g2w[3]};
        float4 xreg;

        auto loadW = [&](int k0) {
#pragma unroll
            for (int r = 0; r < 4; ++r) {
                int f  = r*1024 + t*4;
                int m  = f >> 4;
                int kk = f & 15;
                wreg[r] = *(const float4*)&c1w[(size_t)m*CC + k0 + kk];
            }
        };
        auto loadF = [&](int k0) {
            const float* fb = feats + (frow_base + k0 + kk0)*NN;
            xreg.x = fb[sidx4.x];
            xreg.y = fb[sidx4.y];
            xreg.z = fb[sidx4.z];
            xreg.w = fb[sidx4.w];
        };
        auto stage_write = [&](float* base) {
            float* sWb = base;
            float* sFb = base + G2_KC*G2_LD;
#pragma unroll
            for (int r = 0; r < 4; ++r) {
                int f  = r*1024 + t*4;
                int m  = f >> 4;
                int kk = f & 15;
                float tmp[4] = {wreg[r].x, wreg[r].y, wreg[r].z, wreg[r].w};
#pragma unroll
                for (int u = 0; u < 4; ++u)
                    sWb[(kk+u)*G2_LD + m] = tmp[u];
            }
            *(float4*)&sFb[kk0*G2_TN + j0] = xreg;
        };

        loadF(0);                       // W chunk0 already in g2w (pre-spin)
        stage_write(smf);
        __syncthreads();

        for (int c = 0; c < CC/G2_KC; ++c) {
            const int cur = c & 1;
            float* bcur = smf + cur*G2_BUF;
            float* bnxt = smf + (cur^1)*G2_BUF;

            if (c + 1 < CC/G2_KC) { loadW((c+1)*G2_KC); loadF((c+1)*G2_KC); }

            const float* sWc = bcur;
            const float* sFc = bcur + G2_KC*G2_LD;
#pragma unroll 8
            for (int kk = 0; kk < G2_KC; ++kk) {
                const float4 a0 = *(const float4*)(sWc + kk*G2_LD + tm*8);
                const float4 a1 = *(const float4*)(sWc + kk*G2_LD + tm*8 + 4);
                const float4 f0 = *(const float4*)(sFc + kk*G2_TN + tn*8);
                const float4 f1 = *(const float4*)(sFc + kk*G2_TN + tn*8 + 4);
                float av[8] = {a0.x,a0.y,a0.z,a0.w,a1.x,a1.y,a1.z,a1.w};
                v2f bv2[4] = {{f0.x,f0.y},{f0.z,f0.w},{f1.x,f1.y},{f1.z,f1.w}};
#pragma unroll
                for (int i = 0; i < 8; ++i) {
                    v2f ai = {av[i], av[i]};
#pragma unroll
                    for (int jp = 0; jp < 4; ++jp)
                        acc2[i][jp] += ai * bv2[jp];   // per-column k-order == scalar => bit-identical
                }
            }

            if (c + 1 < CC/G2_KC) stage_write(bnxt);
            __syncthreads();
        }

        float part[3][8];
#pragma unroll
        for (int r = 0; r < 3; ++r)
#pragma unroll
            for (int j = 0; j < 8; ++j) part[r][j] = 0.f;

#pragma unroll
        for (int i = 0; i < 8; ++i) {
            int m = tm*8 + i;
            float scale = __fdiv_rn(bng[m], __fsqrt_rn(__fadd_rn(bnv[m], 1e-5f)));
            float shift = __fsub_rn(bnb[m], __fmul_rn(bnm[m], scale));
            float w0 = c2w[m], w1 = c2w[CC + m], w2 = c2w[2*CC + m];
            float b1m = c1b[m];
#pragma unroll
            for (int j = 0; j < 8; ++j) {
                float x = __fadd_rn(acc2[i][j>>1][j&1], b1m);
                float y = __fadd_rn(__fmul_rn(x, scale), shift);
                float h = y > 0.f ? y : 0.f;
                part[0][j] = fmaf(w0, h, part[0][j]);
                part[1][j] = fmaf(w1, h, part[1][j]);
                part[2][j] = fmaf(w2, h, part[2][j]);
            }
        }
#pragma unroll
        for (int r = 0; r < 3; ++r) {
            float4 p0 = {part[r][0], part[r][1], part[r][2], part[r][3]};
            float4 p1 = {part[r][4], part[r][5], part[r][6], part[r][7]};
            *(float4*)(psum + (r*32 + tm)*PS_LD + tn*8)     = p0;
            *(float4*)(psum + (r*32 + tm)*PS_LD + tn*8 + 4) = p1;
        }
        __syncthreads();
        if (t < 192) {
            int r = t >> 6, col = t & 63;
            float s = 0.f;
#pragma unroll
            for (int w = 0; w < 32; ++w) s = __fadd_rn(s, psum[(r*32 + w)*PS_LD + col]);
            float tot = __fadd_rn(s, c2b[r]);
            gout[r*64 + col] = tot;
            o6[((size_t)bi*SS + n0 + col)*3 + r] = tot;
        }
        __syncthreads();
        // template views (exact double math, cast to f32 — matches _grasp_views)
        for (int i = t; i < NV; i += 256) {
            double phi = (sqrt(5.0) - 1.0) * 0.5;
            double zd  = (2.0*(double)i + 1.0)/300.0 - 1.0;
            double rr  = sqrt(fmax(1.0 - zd*zd, 0.0));
            double ang = 2.0 * 3.14159265358979323846 * (double)i * phi;
            float fx = (float)(rr * cos(ang));
            float fy = (float)(rr * sin(ang));
            float fz = (float)zd;
            float nr = __fsqrt_rn(__fadd_rn(__fadd_rn(__fmul_rn(fx,fx), __fmul_rn(fy,fy)), __fmul_rn(fz,fz)));
            float dn = fmaxf(nr, 1e-8f);
            tv[i]       = __fdiv_rn(fx, dn);
            tv[NV + i]  = __fdiv_rn(fy, dn);
            tv[2*NV + i]= __fdiv_rn(fz, dn);
        }
        __syncthreads();
        if (t < 64) {
            int col = t;
            int sg = bi*SS + n0 + col;
            float vx = gout[col], vy = gout[64 + col], vz = gout[128 + col];

            float nr = __fsqrt_rn(__fadd_rn(__fadd_rn(__fmul_rn(vx,vx), __fmul_rn(vy,vy)), __fmul_rn(vz,vz)));
            float dn = fmaxf(nr, 1e-8f);
            float ux = __fdiv_rn(vx, dn), uy = __fdiv_rn(vy, dn), uz = __fdiv_rn(vz, dn);
            float best = -INFINITY; int bidx = 0;
            for (int v = 0; v < NV; ++v) {
                float cde = __fadd_rn(__fadd_rn(__fmul_rn(ux, tv[v]), __fmul_rn(uy, tv[NV+v])), __fmul_rn(uz, tv[2*NV+v]));
                if (cde > best) { best = cde; bidx = v; }
            }
            o7[sg] = (float)bidx;

            float axx = -vx, axy = -vy, axz = -vz;
            float ayx = vy, ayy = -vx, ayz = 0.f;
            float s2 = __fadd_rn(__fadd_rn(__fmul_rn(ayx,ayx), __fmul_rn(ayy,ayy)), 0.f);
            if (s2 == 0.f) { ayx = 0.f; ayy = 1.f; ayz = 0.f; }
            float an = __fsqrt_rn(__fadd_rn(__fadd_rn(__fmul_rn(axx,axx), __fmul_rn(axy,axy)), __fmul_rn(axz,axz)));
            float nx0 = __fdiv_rn(axx, an), nx1 = __fdiv_rn(axy, an), nx2 = __fdiv_rn(axz, an);
            float bn2 = __fsqrt_rn(__fadd_rn(__fadd_rn(__fmul_rn(ayx,ayx), __fmul_rn(ayy,ayy)), __fmul_rn(ayz,ayz)));
            float ny0 = __fdiv_rn(ayx, bn2), ny1 = __fdiv_rn(ayy, bn2), ny2 = __fdiv_rn(ayz, bn2);
            float nz0 = __fsub_rn(__fmul_rn(nx1, ny2), __fmul_rn(nx2, ny1));
            float nz1 = __fsub_rn(__fmul_rn(nx2, ny0), __fmul_rn(nx0, ny2));
            float nz2 = __fsub_rn(__fmul_rn(nx0, ny1), __fmul_rn(nx1, ny0));
            size_t o = (size_t)sg * 9;
            o8[o+0] = nx0; o8[o+1] = ny0; o8[o+2] = nz0;
            o8[o+3] = nx1; o8[o+4] = ny1; o8[o+5] = nz1;
            o8[o+6] = nx2; o8[o+7] = ny2; o8[o+8] = nz2;
        }
    } else {
        // ---------------- gathers: o2 / o4 / o5 (188 blocks) ----------------
        const int NQ = (BB*CC*SS) / 4;          // 262144 quads
        for (int q = (wid - 64)*256 + t; q < NQ; q += 188*256) {
            int e = q << 2;
            int b = e >> 18;
            int r = e & ((1 << 18) - 1);
            int c = r >> 10;
            int s = r & 1023;
            int4 i4 = *(const int4*)&indsp[(b << 10) + s];
            const float* fb = feats + ((size_t)b*CC + c)*NN;
            float4 v = { fb[i4.x], fb[i4.y], fb[i4.z], fb[i4.w] };
            *(float4*)&o4[e] = v;
            if (c == 0) {
                const float* gb = o1 + (size_t)b*NN;
                float4 g4 = { gb[i4.x], gb[i4.y], gb[i4.z], gb[i4.w] };
                *(float4*)&o5[(b << 10) + s] = g4;
                const float* xb = xyz + (size_t)b*NN*3;
                float o2buf[12];
                int ii[4] = { i4.x, i4.y, i4.z, i4.w };
#pragma unroll
                for (int k = 0; k < 4; ++k) {
                    o2buf[k*3+0] = xb[(size_t)ii[k]*3 + 0];
                    o2buf[k*3+1] = xb[(size_t)ii[k]*3 + 1];
                    o2buf[k*3+2] = xb[(size_t)ii[k]*3 + 2];
                }
                float* dst = o2 + ((size_t)(b << 10) + s)*3;
                *(float4*)&dst[0] = *(float4*)&o2buf[0];
                *(float4*)&dst[4] = *(float4*)&o2buf[4];
                *(float4*)&dst[8] = *(float4*)&o2buf[8];
            }
        }
    }
}

// ---------------------------------------------------------------------------
extern "C" void kernel_launch(void* const* d_in, const int* in_sizes, int n_in,
                              void* d_out, int out_size, void* d_ws, size_t ws_size,
                              hipStream_t stream) {
    const float* xyz   = (const float*)d_in[0];
    const float* feats = (const float*)d_in[1];
    const float* gh_w1 = (const float*)d_in[2];
    const float* gh_b1 = (const float*)d_in[3];
    const float* gh_g  = (const float*)d_in[4];
    const float* gh_be = (const float*)d_in[5];
    const float* gh_m  = (const float*)d_in[6];
    const float* gh_v  = (const float*)d_in[7];
    const float* gh_w2 = (const float*)d_in[8];
    const float* gh_b2 = (const float*)d_in[9];
    const float* c1_w  = (const float*)d_in[10];
    const float* c1_b  = (const float*)d_in[11];
    const float* bn_g  = (const float*)d_in[12];
    const float* bn_b  = (const float*)d_in[13];
    const float* bn_m  = (const float*)d_in[14];
    const float* bn_v  = (const float*)d_in[15];
    const float* c2_w  = (const float*)d_in[16];
    const float* c2_b  = (const float*)d_in[17];

    float* out = (float*)d_out;
    float* o0 = out + O0;
    float* o1 = out + O1;
    float* o2 = out + O2;
    float* o3 = out + O3;
    float* o4 = out + O4;
    float* o5 = out + O5;
    float* o6 = out + O6;
    float* o7 = out + O7;
    float* o8 = out + O8;

    char* ws = (char*)d_ws;
    size_t off = 0;
    auto take = [&](size_t bytes) -> char* {
        char* p = ws + off;
        off = (off + bytes + 255) & ~(size_t)255;
        return p;
    };
    int*   corig = (int*)take((size_t)BB*NN*4);
    float* cx    = (float*)take((size_t)BB*NN*4);
    float* cy    = (float*)take((size_t)BB*NN*4);
    float* cz    = (float*)take((size_t)BB*NN*4);
    int*   indsp = (int*)take((size_t)BB*SS*4);
    int*   donep = (int*)take(64);

    // 1) fused conv+bn+relu+conv over all N points -> o0, o1
    gemm_fused<<<dim3((NN + G1_TN - 1)/G1_TN, BB), 256, 0, stream>>>(
        feats, gh_w1, gh_b1, gh_g, gh_be, gh_m, gh_v, gh_w2, gh_b2, o0, o1);

    // 2) mega: compact+FPS (4 blocks) || spin -> gemm2+view (64) & gathers (188)
    hipMemsetAsync(donep, 0, 4, stream);
    mega_kernel<<<dim3(256), 256, 0, stream>>>(
        xyz, feats, o0, o1,
        c1_w, c1_b, bn_g, bn_b, bn_m, bn_v, c2_w, c2_b,
        corig, cx, cy, cz,
        o2, o3, o4, o5, o6, o7, o8, indsp, donep);
}

// Round 5
// 931.401 us; speedup vs baseline: 11.9562x; 11.9562x over previous
//
#include <hip/hip_runtime.h>
#include <hip/hip_bf16.h>
#include <math.h>

static constexpr int BB = 4;
static constexpr int NN = 20000;
static constexpr int CC = 256;
static constexpr int SS = 1024;   // NUM_SAMPLE
static constexpr int NV = 300;    // NUM_VIEW

// output offsets (floats) in d_out, concatenated in reference return order
static constexpr size_t O0 = 0;                     // objectness (B,2,N)
static constexpr size_t O1 = O0 + (size_t)BB*2*NN;  // graspness (B,N)
static constexpr size_t O2 = O1 + (size_t)BB*NN;    // graspable_xyz (B,S,3)
static constexpr size_t O3 = O2 + (size_t)BB*SS*3;  // graspable_inds (B,S) as float
static constexpr size_t O4 = O3 + (size_t)BB*SS;    // graspable_features (B,C,S)
static constexpr size_t O5 = O4 + (size_t)BB*CC*SS; // fp2_graspness (B,S)
static constexpr size_t O6 = O5 + (size_t)BB*SS;    // vp_xyz (B,S,3)
static constexpr size_t O7 = O6 + (size_t)BB*SS*3;  // top_view_inds (B,S) as float
static constexpr size_t O8 = O7 + (size_t)BB*SS;    // vp_rot (B,S,3,3)

typedef float v2f __attribute__((ext_vector_type(2)));

// constants shared with mega's gemm2 epilogue layout
static constexpr int KC = 32;     // legacy offset constant (tv placement)
static constexpr int SW_LD = 260; // legacy offset constant
static constexpr int PS_LD = 68;  // padded LDS row for psum

// ---------------------------------------------------------------------------
// GEMM1 (R1-proven, measured ~247us): 256x64 tile, pipelined double-buffered
// staging + packed-f32 FMA. KC=16, two buffers; loads for chunk c+1 issue
// before compute of chunk c; one barrier per chunk. acc as v2f[8][4]:
// 32 v_pk_fma_f32 per kk; per-(i,j) k-order identical to scalar chain =>
// o0/o1 BIT-IDENTICAL => mask/FPS unchanged.
// NOTE (R4 lesson): register-tile variants must be sized against the
// __launch_bounds__ VGPR cap — acc[64] @ (256,2) spilled to scratch (28 GB
// of traffic, 10.5 ms). This shape uses ~84 VGPRs: safe at 2 blocks/CU.
// ---------------------------------------------------------------------------
static constexpr int G1_TN  = 64;
static constexpr int G1_KC  = 16;
static constexpr int G1_LD  = 260;                      // 2-way-free transpose writes, 16B-aligned rows
static constexpr int G1_BUF = G1_KC*G1_LD + G1_KC*G1_TN; // floats per buffer = 5184

__global__ __launch_bounds__(256, 2) void gemm_fused(
    const float* __restrict__ X,
    const float* __restrict__ W1, const float* __restrict__ B1v,
    const float* __restrict__ Gv, const float* __restrict__ BEv,
    const float* __restrict__ Mv, const float* __restrict__ Vv,
    const float* __restrict__ W2, const float* __restrict__ B2v,
    float* __restrict__ o0, float* __restrict__ o1)
{
    __shared__ alignas(16) float smem[2*G1_BUF];        // 41472 B
    float* psum = smem;                                  // [3][32][PS_LD] alias (post-loop)
    float* gout = smem + 3*32*PS_LD;                     // [3][64]

    const int t  = threadIdx.x;
    const int b  = blockIdx.y;
    const int n0 = blockIdx.x * G1_TN;
    const int tm = t & 31;
    const int tn = t >> 5;
    const float* Xb = X + (size_t)b * CC * NN;
    const bool full = (n0 + G1_TN <= NN);

    v2f acc2[8][4];
#pragma unroll
    for (int i = 0; i < 8; ++i)
#pragma unroll
        for (int jp = 0; jp < 4; ++jp) acc2[i][jp] = (v2f){0.f, 0.f};

    float4 wreg[4];
    float4 xreg;

    auto stage_load = [&](int k0) {
#pragma unroll
        for (int r = 0; r < 4; ++r) {
            int f  = r*1024 + t*4;           // float index into 256x16 W-slice
            int m  = f >> 4;                 // 0..255
            int kk = f & 15;                 // 0,4,8,12 (4-aligned)
            wreg[r] = *(const float4*)&W1[(size_t)m*CC + k0 + kk];
        }
        int fx = t*4;                        // float index into 16x64 X-slice
        int kk = fx >> 6;                    // 0..15
        int j  = fx & 63;                    // 4-aligned
        if (full) {
            xreg = *(const float4*)&Xb[(size_t)(k0+kk)*NN + n0 + j];
        } else {
            float tmp[4];
#pragma unroll
            for (int u = 0; u < 4; ++u) {
                int col = n0 + j + u;
                tmp[u] = (col < NN) ? Xb[(size_t)(k0+kk)*NN + col] : 0.f;
            }
            xreg = make_float4(tmp[0], tmp[1], tmp[2], tmp[3]);
        }
    };

    auto stage_write = [&](float* sWb, float* sFb) {
#pragma unroll
        for (int r = 0; r < 4; ++r) {
            int f  = r*1024 + t*4;
            int m  = f >> 4;
            int kk = f & 15;
            float tmp[4] = {wreg[r].x, wreg[r].y, wreg[r].z, wreg[r].w};
#pragma unroll
            for (int u = 0; u < 4; ++u)
                sWb[(kk+u)*G1_LD + m] = tmp[u];   // transpose; 2-way-free banks at LD=260
        }
        int fx = t*4;
        int kk = fx >> 6;
        int j  = fx & 63;
        *(float4*)&sFb[kk*G1_TN + j] = xreg;
    };

    // prologue: chunk 0 into buffer 0
    stage_load(0);
    stage_write(smem, smem + G1_KC*G1_LD);
    __syncthreads();

    for (int c = 0; c < CC/G1_KC; ++c) {
        const int cur = c & 1;
        float* base_cur = smem + cur*G1_BUF;
        float* base_nxt = smem + (cur^1)*G1_BUF;

        if (c + 1 < CC/G1_KC) stage_load((c+1)*G1_KC);   // latency hides under compute

        const float* sWc = base_cur;
        const float* sFc = base_cur + G1_KC*G1_LD;
#pragma unroll 8
        for (int kk = 0; kk < G1_KC; ++kk) {
            const float4 a0 = *(const float4*)(sWc + kk*G1_LD + tm*8);
            const float4 a1 = *(const float4*)(sWc + kk*G1_LD + tm*8 + 4);
            const float4 f0 = *(const float4*)(sFc + kk*G1_TN + tn*8);
            const float4 f1 = *(const float4*)(sFc + kk*G1_TN + tn*8 + 4);
            float av[8] = {a0.x,a0.y,a0.z,a0.w,a1.x,a1.y,a1.z,a1.w};
            v2f bv2[4] = {{f0.x,f0.y},{f0.z,f0.w},{f1.x,f1.y},{f1.z,f1.w}};
#pragma unroll
            for (int i = 0; i < 8; ++i) {
                v2f ai = {av[i], av[i]};
#pragma unroll
                for (int jp = 0; jp < 4; ++jp)
                    acc2[i][jp] += ai * bv2[jp];     // v_pk_fma_f32; per-column math == scalar order
            }
        }

        if (c + 1 < CC/G1_KC) stage_write(base_nxt, base_nxt + G1_KC*G1_LD);
        __syncthreads();
    }

    float part[3][8];
#pragma unroll
    for (int r = 0; r < 3; ++r)
#pragma unroll
        for (int j = 0; j < 8; ++j) part[r][j] = 0.f;

#pragma unroll
    for (int i = 0; i < 8; ++i) {
        int m = tm*8 + i;
        float scale = __fdiv_rn(Gv[m], __fsqrt_rn(__fadd_rn(Vv[m], 1e-5f)));
        float shift = __fsub_rn(BEv[m], __fmul_rn(Mv[m], scale));
        float w0 = W2[m], w1 = W2[CC + m], w2 = W2[2*CC + m];
        float b1m = B1v[m];
#pragma unroll
        for (int j = 0; j < 8; ++j) {
            float x = __fadd_rn(acc2[i][j>>1][j&1], b1m);
            float y = __fadd_rn(__fmul_rn(x, scale), shift);
            float h = y > 0.f ? y : 0.f;
            part[0][j] = fmaf(w0, h, part[0][j]);
            part[1][j] = fmaf(w1, h, part[1][j]);
            part[2][j] = fmaf(w2, h, part[2][j]);
        }
    }
#pragma unroll
    for (int r = 0; r < 3; ++r) {
        float4 p0 = {part[r][0], part[r][1], part[r][2], part[r][3]};
        float4 p1 = {part[r][4], part[r][5], part[r][6], part[r][7]};
        *(float4*)(psum + (r*32 + tm)*PS_LD + tn*8)     = p0;
        *(float4*)(psum + (r*32 + tm)*PS_LD + tn*8 + 4) = p1;
    }
    __syncthreads();
    if (t < 192) {
        int r = t >> 6, col = t & 63;
        float s = 0.f;
#pragma unroll
        for (int w = 0; w < 32; ++w) s = __fadd_rn(s, psum[(r*32 + w)*PS_LD + col]);
        float tot = __fadd_rn(s, B2v[r]);
        gout[r*64 + col] = tot;
    }
    __syncthreads();
    if (t < 64) {
        int n = n0 + t;
        if (n < NN) {
            o0[(size_t)b*2*NN + n]      = gout[t];
            o0[(size_t)b*2*NN + NN + n] = gout[64 + t];
            o1[(size_t)b*NN + n]        = gout[128 + t];
        }
    }
}

// ---------------------------------------------------------------------------
// FPS helpers (R6-proven): u64-key DPP wave max, packed-pair scan
// ---------------------------------------------------------------------------
static constexpr int FPS_T = 256;
static constexpr int KAMAX = 20;
static constexpr int CAPA  = FPS_T * KAMAX; // 5120

template<int CTRL>
__device__ __forceinline__ unsigned long long dpp_umax(unsigned long long k) {
    int lo = __builtin_amdgcn_update_dpp(0, (int)(unsigned)k,         CTRL, 0xf, 0xf, false);
    int hi = __builtin_amdgcn_update_dpp(0, (int)(unsigned)(k >> 32), CTRL, 0xf, 0xf, false);
    unsigned long long ok = ((unsigned long long)(unsigned)hi << 32) | (unsigned)lo;
    return ok > k ? ok : k;
}

__device__ __forceinline__ unsigned long long wave_umax_dpp(unsigned long long k) {
    k = dpp_umax<0x111>(k);
    k = dpp_umax<0x112>(k);
    k = dpp_umax<0x114>(k);
    k = dpp_umax<0x118>(k);
    k = dpp_umax<0x142>(k);
    k = dpp_umax<0x143>(k);  // lane 63 has wave max
    return k;
}

__device__ __forceinline__ unsigned long long pack_key(float v, int i) {
    unsigned long long k = (((unsigned long long)__float_as_uint(v)) << 32)
                         | (unsigned long long)(0xFFFFFFFFu - (unsigned)i);
    return (v == -INFINITY) ? 0ull : k;
}

template<int KP>   // pairs of slots per thread
__device__ __forceinline__ void fps_scan_loop(
    int cnt, const float* __restrict__ sxyz,
    unsigned long long (*swk)[4], int* __restrict__ whist)
{
#pragma clang fp contract(off)
    const int t = threadIdx.x;
    const int wave = t >> 6, lane = t & 63;

    v2f X2[KP], Y2[KP], Z2[KP], D2[KP];
#pragma unroll
    for (int jp = 0; jp < KP; ++jp) {
        int g0 = t + ((2*jp) << 8);
        int g1 = g0 + 256;
        bool v0 = g0 < cnt, v1 = g1 < cnt;
        float4 wa = v0 ? *(const float4*)&sxyz[g0*4] : make_float4(0.f,0.f,0.f,0.f);
        float4 wb = v1 ? *(const float4*)&sxyz[g1*4] : make_float4(0.f,0.f,0.f,0.f);
        X2[jp][0] = wa.x; X2[jp][1] = wb.x;
        Y2[jp][0] = wa.y; Y2[jp][1] = wb.y;
        Z2[jp][0] = wa.z; Z2[jp][1] = wb.z;
        D2[jp][0] = v0 ? 1e10f : -INFINITY;
        D2[jp][1] = v1 ? 1e10f : -INFINITY;
    }

    float px = sxyz[0], py = sxyz[1], pz = sxyz[2];

    for (int it = 1; it < SS; ++it) {
        float bv = -INFINITY; int bi = 0x7fffffff;
#pragma unroll
        for (int jp = 0; jp < KP; ++jp) {
            v2f dx = X2[jp] - px;
            v2f dy = Y2[jp] - py;
            v2f dz = Z2[jp] - pz;
            v2f xx = dx*dx, yy = dy*dy;
            v2f sxy = xx + yy;
            v2f zz = dz*dz;
            v2f dd = sxy + zz;              // ((dx^2+dy^2)+dz^2), np order
            float dn0 = fminf(D2[jp][0], dd[0]);
            float dn1 = fminf(D2[jp][1], dd[1]);
            D2[jp][0] = dn0;
            D2[jp][1] = dn1;
            if (dn0 > bv) { bv = dn0; bi = t + ((2*jp)   << 8); }
            if (dn1 > bv) { bv = dn1; bi = t + ((2*jp+1) << 8); }
        }
        unsigned long long key = wave_umax_dpp(pack_key(bv, bi));
        int par = it & 1;
        if (lane == 63) swk[par][wave] = key;
        __syncthreads();
        const ulonglong2* kp = (const ulonglong2*)&swk[par][0];
        ulonglong2 kA = kp[0], kB = kp[1];
        unsigned long long m0 = kA.x > kA.y ? kA.x : kA.y;
        unsigned long long m1 = kB.x > kB.y ? kB.x : kB.y;
        unsigned long long best = m0 > m1 ? m0 : m1;
        int wi = (int)(0xFFFFFFFFu - (unsigned)(best & 0xFFFFFFFFull));
        float4 w4 = *(const float4*)&sxyz[wi*4];
        px = w4.x; py = w4.y; pz = w4.z;
        if (t == 0) whist[it] = wi;
    }
}

// ---------------------------------------------------------------------------
// MEGA kernel (R2-proven, measured ~675us): 256 blocks x 256 threads.
//  blocks [0,BB):   compact (mask from o0/o1) -> FPS -> publish inds (release)
//  blocks [BB,256): low-duty spin on done flag, then acquire and either
//                     wid<64:  gemm2 (pipelined dbuf + pk-FMA; W chunk0
//                              loads issued pre-spin) + view/rot epilogue
//                     else:    o2/o4/o5 gathers (single pass: best line reuse)
// ---------------------------------------------------------------------------
__global__ __launch_bounds__(256, 1) void mega_kernel(
    const float* __restrict__ xyz, const float* __restrict__ feats,
    const float* __restrict__ o0, const float* __restrict__ o1,
    const float* __restrict__ c1w, const float* __restrict__ c1b,
    const float* __restrict__ bng, const float* __restrict__ bnb,
    const float* __restrict__ bnm, const float* __restrict__ bnv,
    const float* __restrict__ c2w, const float* __restrict__ c2b,
    int* __restrict__ corig, float* __restrict__ cxg,
    float* __restrict__ cyg, float* __restrict__ czg,
    float* __restrict__ o2, float* __restrict__ o3, float* __restrict__ o4,
    float* __restrict__ o5, float* __restrict__ o6, float* __restrict__ o7,
    float* __restrict__ o8, int* __restrict__ indsp, int* __restrict__ donep)
{
    __shared__ alignas(16) char sm[86272];
    const int t = threadIdx.x;
    const int wave = t >> 6, lane = t & 63;

    if (blockIdx.x < BB) {
        // =================== FPS PRODUCER BLOCK ===================
        const int b = blockIdx.x;
        const size_t bofs = (size_t)b*NN;
        float* sxyz = (float*)sm;                                     // [CAPA*4]
        int*   whist = (int*)(sm + 81920);                            // [SS]
        unsigned long long (*swk)[4] = (unsigned long long (*)[4])(sm + 86016);
        int*   wsum  = (int*)(sm + 86080);                            // [4]
        int*   smisc = (int*)(sm + 86096);                            // running

        // ---- compact: mask recomputed bit-exactly from o0/o1 ----
        if (t == 0) smisc[0] = 0;
        __syncthreads();
        const float* ob0 = o0 + (size_t)b*2*NN;
        const float* ob1 = o1 + (size_t)b*NN;
        for (int base = 0; base < NN; base += 256) {
            int i = base + t;
            bool valid = i < NN;
            float g1 = valid ? ob1[i]      : 0.f;
            float v0 = valid ? ob0[i]      : 0.f;
            float v1 = valid ? ob0[NN + i] : 0.f;
            bool m = valid && (g1 > 0.1f) && (v1 > v0);
            unsigned long long bal = __ballot(m);
            int pre = __popcll(bal & ((1ull << lane) - 1ull));
            if (lane == 0) wsum[wave] = __popcll(bal);
            __syncthreads();
            int offs = smisc[0];
            int tilesum = wsum[0] + wsum[1] + wsum[2] + wsum[3];
            for (int ww = 0; ww < wave; ++ww) offs += wsum[ww];
            if (m) {
                int pos = offs + pre;
                float x = xyz[(bofs + i)*3 + 0];
                float y = xyz[(bofs + i)*3 + 1];
                float z = xyz[(bofs + i)*3 + 2];
                corig[bofs + pos] = i;
                cxg[bofs + pos] = x; cyg[bofs + pos] = y; czg[bofs + pos] = z;
                if (pos < CAPA) {
                    float4 w4 = {x, y, z, 0.f};
                    *(float4*)&sxyz[pos*4] = w4;
                }
            }
            __syncthreads();
            if (t == 0) smisc[0] += tilesum;   // no post-scatter wsum read (race-free)
        }
        __syncthreads();
        const int cnt = smisc[0];

        float* o3b = o3 + (size_t)b*SS;
        int*   oib = indsp + (size_t)b*SS;

        if (cnt <= 0) {
            for (int s = t; s < SS; s += FPS_T) { o3b[s] = 0.f; oib[s] = 0; }
            __syncthreads();
            if (t == 0) {
                __threadfence();
                __hip_atomic_fetch_add(donep, 1, __ATOMIC_RELEASE, __HIP_MEMORY_SCOPE_AGENT);
            }
            return;
        }

        if (t == 0) whist[0] = 0;
        __syncthreads();

        if (cnt <= CAPA) {
            int kat2 = ((cnt + 255) >> 8);
            kat2 = (kat2 + 1) & ~1;
            int kpn = kat2 >> 1;
            switch (kpn) {
                case 1:  fps_scan_loop<1 >(cnt, sxyz, swk, whist); break;
                case 2:  fps_scan_loop<2 >(cnt, sxyz, swk, whist); break;
                case 3:  fps_scan_loop<3 >(cnt, sxyz, swk, whist); break;
                case 4:  fps_scan_loop<4 >(cnt, sxyz, swk, whist); break;
                case 5:  fps_scan_loop<5 >(cnt, sxyz, swk, whist); break;
                case 6:  fps_scan_loop<6 >(cnt, sxyz, swk, whist); break;
                case 7:  fps_scan_loop<7 >(cnt, sxyz, swk, whist); break;
                case 8:  fps_scan_loop<8 >(cnt, sxyz, swk, whist); break;
                case 9:  fps_scan_loop<9 >(cnt, sxyz, swk, whist); break;
                default: fps_scan_loop<10>(cnt, sxyz, swk, whist); break;
            }
        } else {
            // fallback: LDS distances, streamed xyz from global compacted arrays
            float* Dl = sxyz;
            for (int g = t; g < cnt; g += FPS_T) Dl[g] = 1e10f;
            __syncthreads();
            float px = cxg[bofs], py = cyg[bofs], pz = czg[bofs];
            for (int it = 1; it < SS; ++it) {
                float bv = -INFINITY; int bi = 0x7fffffff;
                for (int g = t; g < cnt; g += FPS_T) {
                    float dx = __fsub_rn(cxg[bofs + g], px);
                    float dy = __fsub_rn(cyg[bofs + g], py);
                    float dz = __fsub_rn(czg[bofs + g], pz);
                    float d  = __fadd_rn(__fadd_rn(__fmul_rn(dx,dx), __fmul_rn(dy,dy)), __fmul_rn(dz,dz));
                    float dn = fminf(Dl[g], d);
                    Dl[g] = dn;
                    if (dn > bv) { bv = dn; bi = g; }
                }
                unsigned long long key = wave_umax_dpp(pack_key(bv, bi));
                int par = it & 1;
                if (lane == 63) swk[par][wave] = key;
                __syncthreads();
                const ulonglong2* kp = (const ulonglong2*)&swk[par][0];
                ulonglong2 kA = kp[0], kB = kp[1];
                unsigned long long m0 = kA.x > kA.y ? kA.x : kA.y;
                unsigned long long m1 = kB.x > kB.y ? kB.x : kB.y;
                unsigned long long best = m0 > m1 ? m0 : m1;
                int wi = (int)(0xFFFFFFFFu - (unsigned)(best & 0xFFFFFFFFull));
                px = cxg[bofs + wi]; py = cyg[bofs + wi]; pz = czg[bofs + wi];
                if (t == 0) whist[it] = wi;
            }
        }

        __syncthreads();
        for (int s = t; s < SS; s += FPS_T) {
            int wi  = whist[s];
            int org = corig[bofs + wi];
            oib[s] = org;
            o3b[s] = (float)org;
        }
        __syncthreads();                 // all inds writes issued & drained
        if (t == 0) {
            __threadfence();             // agent-scope flush of this block's stores
            __hip_atomic_fetch_add(donep, 1, __ATOMIC_RELEASE, __HIP_MEMORY_SCOPE_AGENT);
        }
        return;
    }

    // =================== CONSUMER BLOCKS ===================
    const int wid = blockIdx.x - BB;

    // pre-stage gemm2 W chunk-0 loads (independent of producers; in flight
    // during the spin window)
    float4 g2w[4];
    if (wid < 64) {
#pragma unroll
        for (int r = 0; r < 4; ++r) {
            int f  = r*1024 + t*4;
            int m  = f >> 4;
            int kk = f & 15;
            g2w[r] = *(const float4*)&c1w[(size_t)m*CC + kk];
        }
    }

    {
        int* smisc = (int*)(sm + 86096);
        if (t == 0) smisc[1] = 0;
        __syncthreads();
        // low-duty spin (R4/R6-proven clock-friendly point)
        float a = 1.0f + (float)t * 1e-6f, bmul = 1.0000001f, c = 0.f;
        for (int iter = 0; iter < (1 << 22); ++iter) {
#pragma unroll
            for (int u = 0; u < 16; ++u) c = fmaf(a, bmul, c);
            __builtin_amdgcn_s_sleep(8);
            if (t == 0 && (iter & 7) == 0) {
                if (__hip_atomic_load(donep, __ATOMIC_RELAXED, __HIP_MEMORY_SCOPE_AGENT) >= BB)
                    *(volatile int*)&smisc[1] = 1;
            }
            if (*(volatile int*)&smisc[1]) break;
        }
        ((volatile float*)(sm + 86144))[t & 31] = c;   // keep spin live; scratch above live regions
        __syncthreads();
        (void)__hip_atomic_load(donep, __ATOMIC_ACQUIRE, __HIP_MEMORY_SCOPE_AGENT);
    }

    if (wid < 64) {
        // ---------------- gemm2 + view/rot for one 64-col tile ----------------
        const int bi = wid >> 4;
        const int n0 = (wid & 15) << 6;
        constexpr int G2_KC  = 16;
        constexpr int G2_LD  = 260;
        constexpr int G2_TN  = 64;
        constexpr int G2_BUF = G2_KC*G2_LD + G2_KC*G2_TN;  // 5184 floats/buffer

        float* smf  = (float*)sm;                          // 2 buffers: 41472 B
        float* psum = smf;                                 // [3][32][PS_LD] (post-loop alias)
        float* gout = (float*)(sm + 3*32*PS_LD*4);         // [3][64]
        float* tv   = (float*)(sm + KC*SW_LD*4);           // [3][300] (post-loop alias)

        const int tm  = t & 31;
        const int tn  = t >> 5;
        const int kk0 = t >> 4;          // F-stage row (0..15)
        const int j0  = (t*4) & 63;      // F-stage col base (4-aligned)

        const int4 sidx4 = *(const int4*)&indsp[(bi << 10) + n0 + j0];
        const size_t frow_base = (size_t)bi * CC;

        v2f acc2[8][4];
#pragma unroll
        for (int i = 0; i < 8; ++i)
#pragma unroll
            for (int jp = 0; jp < 4; ++jp) acc2[i][jp] = (v2f){0.f, 0.f};

        float4 wreg[4] = {g2w[0], g2w[1], g2w[2], g2w[3]};
        float4 xreg;

        auto loadW = [&](int k0) {
#pragma unroll
            for (int r = 0; r < 4; ++r) {
                int f  = r*1024 + t*4;
                int m  = f >> 4;
                int kk = f & 15;
                wreg[r] = *(const float4*)&c1w[(size_t)m*CC + k0 + kk];
            }
        };
        auto loadF = [&](int k0) {
            const float* fb = feats + (frow_base + k0 + kk0)*NN;
            xreg.x = fb[sidx4.x];
            xreg.y = fb[sidx4.y];
            xreg.z = fb[sidx4.z];
            xreg.w = fb[sidx4.w];
        };
        auto stage_write = [&](float* base) {
            float* sWb = base;
            float* sFb = base + G2_KC*G2_LD;
#pragma unroll
            for (int r = 0; r < 4; ++r) {
                int f  = r*1024 + t*4;
                int m  = f >> 4;
                int kk = f & 15;
                float tmp[4] = {wreg[r].x, wreg[r].y, wreg[r].z, wreg[r].w};
#pragma unroll
                for (int u = 0; u < 4; ++u)
                    sWb[(kk+u)*G2_LD + m] = tmp[u];
            }
            *(float4*)&sFb[kk0*G2_TN + j0] = xreg;
        };

        loadF(0);                       // W chunk0 already in g2w (pre-spin)
        stage_write(smf);
        __syncthreads();

        for (int c = 0; c < CC/G2_KC; ++c) {
            const int cur = c & 1;
            float* bcur = smf + cur*G2_BUF;
            float* bnxt = smf + (cur^1)*G2_BUF;

            if (c + 1 < CC/G2_KC) { loadW((c+1)*G2_KC); loadF((c+1)*G2_KC); }

            const float* sWc = bcur;
            const float* sFc = bcur + G2_KC*G2_LD;
#pragma unroll 8
            for (int kk = 0; kk < G2_KC; ++kk) {
                const float4 a0 = *(const float4*)(sWc + kk*G2_LD + tm*8);
                const float4 a1 = *(const float4*)(sWc + kk*G2_LD + tm*8 + 4);
                const float4 f0 = *(const float4*)(sFc + kk*G2_TN + tn*8);
                const float4 f1 = *(const float4*)(sFc + kk*G2_TN + tn*8 + 4);
                float av[8] = {a0.x,a0.y,a0.z,a0.w,a1.x,a1.y,a1.z,a1.w};
                v2f bv2[4] = {{f0.x,f0.y},{f0.z,f0.w},{f1.x,f1.y},{f1.z,f1.w}};
#pragma unroll
                for (int i = 0; i < 8; ++i) {
                    v2f ai = {av[i], av[i]};
#pragma unroll
                    for (int jp = 0; jp < 4; ++jp)
                        acc2[i][jp] += ai * bv2[jp];   // per-column k-order == scalar => bit-identical
                }
            }

            if (c + 1 < CC/G2_KC) stage_write(bnxt);
            __syncthreads();
        }

        float part[3][8];
#pragma unroll
        for (int r = 0; r < 3; ++r)
#pragma unroll
            for (int j = 0; j < 8; ++j) part[r][j] = 0.f;

#pragma unroll
        for (int i = 0; i < 8; ++i) {
            int m = tm*8 + i;
            float scale = __fdiv_rn(bng[m], __fsqrt_rn(__fadd_rn(bnv[m], 1e-5f)));
            float shift = __fsub_rn(bnb[m], __fmul_rn(bnm[m], scale));
            float w0 = c2w[m], w1 = c2w[CC + m], w2 = c2w[2*CC + m];
            float b1m = c1b[m];
#pragma unroll
            for (int j = 0; j < 8; ++j) {
                float x = __fadd_rn(acc2[i][j>>1][j&1], b1m);
                float y = __fadd_rn(__fmul_rn(x, scale), shift);
                float h = y > 0.f ? y : 0.f;
                part[0][j] = fmaf(w0, h, part[0][j]);
                part[1][j] = fmaf(w1, h, part[1][j]);
                part[2][j] = fmaf(w2, h, part[2][j]);
            }
        }
#pragma unroll
        for (int r = 0; r < 3; ++r) {
            float4 p0 = {part[r][0], part[r][1], part[r][2], part[r][3]};
            float4 p1 = {part[r][4], part[r][5], part[r][6], part[r][7]};
            *(float4*)(psum + (r*32 + tm)*PS_LD + tn*8)     = p0;
            *(float4*)(psum + (r*32 + tm)*PS_LD + tn*8 + 4) = p1;
        }
        __syncthreads();
        if (t < 192) {
            int r = t >> 6, col = t & 63;
            float s = 0.f;
#pragma unroll
            for (int w = 0; w < 32; ++w) s = __fadd_rn(s, psum[(r*32 + w)*PS_LD + col]);
            float tot = __fadd_rn(s, c2b[r]);
            gout[r*64 + col] = tot;
            o6[((size_t)bi*SS + n0 + col)*3 + r] = tot;
        }
        __syncthreads();
        // template views (exact double math, cast to f32 — matches _grasp_views)
        for (int i = t; i < NV; i += 256) {
            double phi = (sqrt(5.0) - 1.0) * 0.5;
            double zd  = (2.0*(double)i + 1.0)/300.0 - 1.0;
            double rr  = sqrt(fmax(1.0 - zd*zd, 0.0));
            double ang = 2.0 * 3.14159265358979323846 * (double)i * phi;
            float fx = (float)(rr * cos(ang));
            float fy = (float)(rr * sin(ang));
            float fz = (float)zd;
            float nr = __fsqrt_rn(__fadd_rn(__fadd_rn(__fmul_rn(fx,fx), __fmul_rn(fy,fy)), __fmul_rn(fz,fz)));
            float dn = fmaxf(nr, 1e-8f);
            tv[i]       = __fdiv_rn(fx, dn);
            tv[NV + i]  = __fdiv_rn(fy, dn);
            tv[2*NV + i]= __fdiv_rn(fz, dn);
        }
        __syncthreads();
        if (t < 64) {
            int col = t;
            int sg = bi*SS + n0 + col;
            float vx = gout[col], vy = gout[64 + col], vz = gout[128 + col];

            float nr = __fsqrt_rn(__fadd_rn(__fadd_rn(__fmul_rn(vx,vx), __fmul_rn(vy,vy)), __fmul_rn(vz,vz)));
            float dn = fmaxf(nr, 1e-8f);
            float ux = __fdiv_rn(vx, dn), uy = __fdiv_rn(vy, dn), uz = __fdiv_rn(vz, dn);
            float best = -INFINITY; int bidx = 0;
            for (int v = 0; v < NV; ++v) {
                float cde = __fadd_rn(__fadd_rn(__fmul_rn(ux, tv[v]), __fmul_rn(uy, tv[NV+v])), __fmul_rn(uz, tv[2*NV+v]));
                if (cde > best) { best = cde; bidx = v; }
            }
            o7[sg] = (float)bidx;

            float axx = -vx, axy = -vy, axz = -vz;
            float ayx = vy, ayy = -vx, ayz = 0.f;
            float s2 = __fadd_rn(__fadd_rn(__fmul_rn(ayx,ayx), __fmul_rn(ayy,ayy)), 0.f);
            if (s2 == 0.f) { ayx = 0.f; ayy = 1.f; ayz = 0.f; }
            float an = __fsqrt_rn(__fadd_rn(__fadd_rn(__fmul_rn(axx,axx), __fmul_rn(axy,axy)), __fmul_rn(axz,axz)));
            float nx0 = __fdiv_rn(axx, an), nx1 = __fdiv_rn(axy, an), nx2 = __fdiv_rn(axz, an);
            float bn2 = __fsqrt_rn(__fadd_rn(__fadd_rn(__fmul_rn(ayx,ayx), __fmul_rn(ayy,ayy)), __fmul_rn(ayz,ayz)));
            float ny0 = __fdiv_rn(ayx, bn2), ny1 = __fdiv_rn(ayy, bn2), ny2 = __fdiv_rn(ayz, bn2);
            float nz0 = __fsub_rn(__fmul_rn(nx1, ny2), __fmul_rn(nx2, ny1));
            float nz1 = __fsub_rn(__fmul_rn(nx2, ny0), __fmul_rn(nx0, ny2));
            float nz2 = __fsub_rn(__fmul_rn(nx0, ny1), __fmul_rn(nx1, ny0));
            size_t o = (size_t)sg * 9;
            o8[o+0] = nx0; o8[o+1] = ny0; o8[o+2] = nz0;
            o8[o+3] = nx1; o8[o+4] = ny1; o8[o+5] = nz1;
            o8[o+6] = nx2; o8[o+7] = ny2; o8[o+8] = nz2;
        }
    } else {
        // ---------------- gathers: o2 / o4 / o5 (188 blocks) ----------------
        const int NQ = (BB*CC*SS) / 4;          // 262144 quads
        for (int q = (wid - 64)*256 + t; q < NQ; q += 188*256) {
            int e = q << 2;
            int b = e >> 18;
            int r = e & ((1 << 18) - 1);
            int c = r >> 10;
            int s = r & 1023;
            int4 i4 = *(const int4*)&indsp[(b << 10) + s];
            const float* fb = feats + ((size_t)b*CC + c)*NN;
            float4 v = { fb[i4.x], fb[i4.y], fb[i4.z], fb[i4.w] };
            *(float4*)&o4[e] = v;
            if (c == 0) {
                const float* gb = o1 + (size_t)b*NN;
                float4 g4 = { gb[i4.x], gb[i4.y], gb[i4.z], gb[i4.w] };
                *(float4*)&o5[(b << 10) + s] = g4;
                const float* xb = xyz + (size_t)b*NN*3;
                float o2buf[12];
                int ii[4] = { i4.x, i4.y, i4.z, i4.w };
#pragma unroll
                for (int k = 0; k < 4; ++k) {
                    o2buf[k*3+0] = xb[(size_t)ii[k]*3 + 0];
                    o2buf[k*3+1] = xb[(size_t)ii[k]*3 + 1];
                    o2buf[k*3+2] = xb[(size_t)ii[k]*3 + 2];
                }
                float* dst = o2 + ((size_t)(b << 10) + s)*3;
                *(float4*)&dst[0] = *(float4*)&o2buf[0];
                *(float4*)&dst[4] = *(float4*)&o2buf[4];
                *(float4*)&dst[8] = *(float4*)&o2buf[8];
            }
        }
    }
}

// ---------------------------------------------------------------------------
extern "C" void kernel_launch(void* const* d_in, const int* in_sizes, int n_in,
                              void* d_out, int out_size, void* d_ws, size_t ws_size,
                              hipStream_t stream) {
    const float* xyz   = (const float*)d_in[0];
    const float* feats = (const float*)d_in[1];
    const float* gh_w1 = (const float*)d_in[2];
    const float* gh_b1 = (const float*)d_in[3];
    const float* gh_g  = (const float*)d_in[4];
    const float* gh_be = (const float*)d_in[5];
    const float* gh_m  = (const float*)d_in[6];
    const float* gh_v  = (const float*)d_in[7];
    const float* gh_w2 = (const float*)d_in[8];
    const float* gh_b2 = (const float*)d_in[9];
    const float* c1_w  = (const float*)d_in[10];
    const float* c1_b  = (const float*)d_in[11];
    const float* bn_g  = (const float*)d_in[12];
    const float* bn_b  = (const float*)d_in[13];
    const float* bn_m  = (const float*)d_in[14];
    const float* bn_v  = (const float*)d_in[15];
    const float* c2_w  = (const float*)d_in[16];
    const float* c2_b  = (const float*)d_in[17];

    float* out = (float*)d_out;
    float* o0 = out + O0;
    float* o1 = out + O1;
    float* o2 = out + O2;
    float* o3 = out + O3;
    float* o4 = out + O4;
    float* o5 = out + O5;
    float* o6 = out + O6;
    float* o7 = out + O7;
    float* o8 = out + O8;

    char* ws = (char*)d_ws;
    size_t off = 0;
    auto take = [&](size_t bytes) -> char* {
        char* p = ws + off;
        off = (off + bytes + 255) & ~(size_t)255;
        return p;
    };
    int*   corig = (int*)take((size_t)BB*NN*4);
    float* cx    = (float*)take((size_t)BB*NN*4);
    float* cy    = (float*)take((size_t)BB*NN*4);
    float* cz    = (float*)take((size_t)BB*NN*4);
    int*   indsp = (int*)take((size_t)BB*SS*4);
    int*   donep = (int*)take(64);

    // 1) fused conv+bn+relu+conv over all N points -> o0, o1
    gemm_fused<<<dim3((NN + G1_TN - 1)/G1_TN, BB), 256, 0, stream>>>(
        feats, gh_w1, gh_b1, gh_g, gh_be, gh_m, gh_v, gh_w2, gh_b2, o0, o1);

    // 2) mega: compact+FPS (4 blocks) || spin -> gemm2+view (64) & gathers (188)
    hipMemsetAsync(donep, 0, 4, stream);
    mega_kernel<<<dim3(256), 256, 0, stream>>>(
        xyz, feats, o0, o1,
        c1_w, c1_b, bn_g, bn_b, bn_m, bn_v, c2_w, c2_b,
        corig, cx, cy, cz,
        o2, o3, o4, o5, o6, o7, o8, indsp, donep);
}